// Round 1
// baseline (256.837 us; speedup 1.0000x reference)
//
#include <hip/hip_runtime.h>
#include <cstddef>

// Problem shape (fixed): N=50000, K=16, C_IN=128, C2=256, C_OUT=128.
#define C_IN  128
#define C2    256
#define C_OUT 128
#define KNBR  16

typedef unsigned short u16;
typedef __attribute__((ext_vector_type(8))) short bf16x8;   // 8 bf16 (4 VGPRs)
typedef __attribute__((ext_vector_type(8))) unsigned short u16x8; // 16B payload
typedef __attribute__((ext_vector_type(4))) float f32x4;

__device__ __forceinline__ float bf2f(u16 h) {
    return __uint_as_float(((unsigned int)h) << 16);
}
__device__ __forceinline__ u16 f2bf(float x) {
    unsigned int u = __float_as_uint(x);
    return (u16)((u + 0x7fffu + ((u >> 16) & 1u)) >> 16);
}

// Transpose + convert weights to bf16, n-major [N][K].
__global__ void prep_k(const float* __restrict__ W1, const float* __restrict__ Ws,
                       const float* __restrict__ Wm, u16* __restrict__ W1t,
                       u16* __restrict__ Wst, u16* __restrict__ Wmt)
{
    const int n = blockIdx.x, t = threadIdx.x;
    if (blockIdx.y == 0) {
        if (t < 128) W1t[n * 128 + t] = f2bf(W1[t * 256 + n]);
    } else if (blockIdx.y == 1) {
        Wst[n * 256 + t] = f2bf(Ws[t * 256 + n]);
    } else {
        if (n < 128) Wmt[n * 256 + t] = f2bf(Wm[t * 128 + n]);
    }
}

// ---------------------------------------------------------------------------
// LESSONS ENCODED:
//  R7:  accumulator arrays indexed by non-unrolled loop vars spill to scratch.
//  R9:  scattered sub-dword global stores -> write-allocate RMW (16x bytes).
//  R10: 1-block/CU weight-stationary waves have zero latency hiding.
//  R11 (this round): gather_k was latency-bound, NOT BW-bound (46% HBM, VGPR=40
//       -> compiler batched the 32 dwordx2 loads, killing MLP). Fix: packed row
//       is now CHANNEL-INTERLEAVED [ey0,x0,ey1,x1,...] so one dwordx4/lane
//       fetches a whole neighbor row (16 loads/wave, 16 KB in flight/wave) and
//       e,x land in the same lane for the FMA.
// packed row (512 u16): 256 pairs of (ey[c], x[c]), both bf16.
// ---------------------------------------------------------------------------

// Fused MLP, 64-row blocks (69.6 KB LDS -> 2 blocks/CU):
//   x  = BN(relu(F @ W1 + b1))  -> xs (LDS)
//   ey = exp(x @ Ws)            -> As reuse -> combined interleaved flush
__global__ __launch_bounds__(256)
void mlp_k(const float* __restrict__ F, const u16* __restrict__ W1t,
           const u16* __restrict__ Wst,
           const float* __restrict__ bias, const float* __restrict__ gamma,
           const float* __restrict__ beta, const float* __restrict__ mean,
           const float* __restrict__ var,
           u16* __restrict__ packed, int N)
{
    __shared__ u16 As[64][136];    // features tile (GEMM1); ey staging (epi 2)
    __shared__ u16 Bs[128][72];    // weight k-slice staging
    __shared__ u16 xs[64][264];    // x tile, full K=256

    const int tid = threadIdx.x;
    const int w = tid >> 6, l = tid & 63, q = l >> 4, r = l & 15;
    const int wm = w & 1, wn = w >> 1;
    const int m0 = blockIdx.x * 64;

    // stage As: 64 x 128 fp32 -> bf16 (2048 float4, 8/thread)
    #pragma unroll
    for (int i = 0; i < 8; i++) {
        int idx = tid + i * 256;
        int row = idx >> 5, c4 = (idx & 31) * 4;
        int gm = m0 + row;
        float4 v = make_float4(0.f, 0.f, 0.f, 0.f);
        if (gm < N) v = *(const float4*)(F + (size_t)gm * C_IN + c4);
        ushort4 h;
        h.x = f2bf(v.x); h.y = f2bf(v.y); h.z = f2bf(v.z); h.w = f2bf(v.w);
        *(ushort4*)&As[row][c4] = h;
    }

    // ---- GEMM1: x = F @ W1, two 128-col halves (nh fully unrolled) ----
    #pragma unroll
    for (int nh = 0; nh < 2; nh++) {
        f32x4 acc[2][4] = {};
        #pragma unroll 1
        for (int k0 = 0; k0 < C_IN; k0 += 64) {
            __syncthreads();   // prior Bs readers done (also covers As stage)
            #pragma unroll
            for (int i = 0; i < 4; i++) {
                int idx = tid + i * 256;
                int row = idx >> 3, g = (idx & 7) * 8;
                *(uint4*)&Bs[row][g] = *(const uint4*)(
                    W1t + (size_t)(nh * 128 + row) * C_IN + k0 + g);
            }
            __syncthreads();
            #pragma unroll
            for (int h = 0; h < 2; h++) {
                bf16x8 af[2], bfr[4];
                #pragma unroll
                for (int i = 0; i < 2; i++)
                    af[i] = *(const bf16x8*)&As[wm * 32 + i * 16 + r][k0 + h * 32 + q * 8];
                #pragma unroll
                for (int j = 0; j < 4; j++)
                    bfr[j] = *(const bf16x8*)&Bs[wn * 64 + j * 16 + r][h * 32 + q * 8];
                #pragma unroll
                for (int i = 0; i < 2; i++)
                    #pragma unroll
                    for (int j = 0; j < 4; j++)
                        acc[i][j] = __builtin_amdgcn_mfma_f32_16x16x32_bf16(
                            af[i], bfr[j], acc[i][j], 0, 0, 0);
            }
        }
        // epilogue 1: BN(relu(z+bias)) -> xs (LDS only)
        #pragma unroll
        for (int j = 0; j < 4; j++) {
            const int ch = nh * 128 + wn * 64 + j * 16 + r;
            const float bi = bias[ch], be = beta[ch], mu = mean[ch];
            const float iv = gamma[ch] * rsqrtf(var[ch] + 1e-5f);
            #pragma unroll
            for (int i = 0; i < 2; i++) {
                const int mb = wm * 32 + i * 16 + q * 4;
                #pragma unroll
                for (int p = 0; p < 4; p++) {
                    float x = fmaxf(acc[i][j][p] + bi, 0.f);
                    x = (x - mu) * iv + be;
                    xs[mb + p][ch] = f2bf(x);
                }
            }
        }
    }
    __syncthreads();   // xs complete (cross-wave) before GEMM2 reads it

    // ---- GEMM2: ey = exp(x @ Ws), A from xs (nh fully unrolled) ----
    #pragma unroll
    for (int nh = 0; nh < 2; nh++) {
        f32x4 acc[2][4] = {};
        #pragma unroll 1
        for (int k0 = 0; k0 < C2; k0 += 64) {
            __syncthreads();   // prior Bs readers / prior-half flush readers done
            #pragma unroll
            for (int i = 0; i < 4; i++) {
                int idx = tid + i * 256;
                int row = idx >> 3, g = (idx & 7) * 8;
                *(uint4*)&Bs[row][g] = *(const uint4*)(
                    Wst + (size_t)(nh * 128 + row) * C2 + k0 + g);
            }
            __syncthreads();
            #pragma unroll
            for (int h = 0; h < 2; h++) {
                bf16x8 af[2], bfr[4];
                #pragma unroll
                for (int i = 0; i < 2; i++)
                    af[i] = *(const bf16x8*)&xs[wm * 32 + i * 16 + r][k0 + h * 32 + q * 8];
                #pragma unroll
                for (int j = 0; j < 4; j++)
                    bfr[j] = *(const bf16x8*)&Bs[wn * 64 + j * 16 + r][h * 32 + q * 8];
                #pragma unroll
                for (int i = 0; i < 2; i++)
                    #pragma unroll
                    for (int j = 0; j < 4; j++)
                        acc[i][j] = __builtin_amdgcn_mfma_f32_16x16x32_bf16(
                            af[i], bfr[j], acc[i][j], 0, 0, 0);
            }
        }
        // epilogue 2: ey -> As reuse (cols local to this nh-half)
        __syncthreads();       // prior As readers (GEMM1 / prev flush) done
        #pragma unroll
        for (int j = 0; j < 4; j++) {
            const int chl = wn * 64 + j * 16 + r;   // 0..127 within half
            #pragma unroll
            for (int i = 0; i < 2; i++) {
                const int mb = wm * 32 + i * 16 + q * 4;
                #pragma unroll
                for (int p = 0; p < 4; p++)
                    As[mb + p][chl] = f2bf(__expf(acc[i][j][p]));
            }
        }
        __syncthreads();       // As (ey half) complete
        // combined interleaved flush for this half:
        // 64 rows x 128 pairs -> 64 x 512 B (2048 uint4, 8/thread).
        // pair (ey[c], x[c]) at packed[row*512 + c*2 .. +1]; this half's pairs
        // occupy the contiguous u16 range [nh*256, nh*256+256).
        #pragma unroll
        for (int i = 0; i < 8; i++) {
            int idx = tid + i * 256;
            int row = idx >> 5, slot = idx & 31;   // slot: uint4 within row-half
            int c0 = slot * 4;                     // first local channel of 4
            if (m0 + row < N) {
                ushort4 e  = *(const ushort4*)&As[row][c0];
                ushort4 xv = *(const ushort4*)&xs[row][nh * 128 + c0];
                uint4 qv;
                qv.x = (unsigned)e.x | ((unsigned)xv.x << 16);
                qv.y = (unsigned)e.y | ((unsigned)xv.y << 16);
                qv.z = (unsigned)e.z | ((unsigned)xv.z << 16);
                qv.w = (unsigned)e.w | ((unsigned)xv.w << 16);
                *(uint4*)(packed + (size_t)(m0 + row) * 512 + nh * 256 + slot * 8) = qv;
            }
        }
    }
}

// Output GEMM, 64-row blocks (59 KB LDS -> 2 blocks/CU):
// out = featb @ Wm + bm. featb aliases out (both 512 B/row); a block reads
// all its A rows before writing them, rows are block-private -> safe.
__global__ __launch_bounds__(256)
void out_gemm(const u16* A, const u16* __restrict__ Bt,
              const float* __restrict__ bias, float* Cf, int N)
{
    __shared__ u16 As[64][72];         //  9.2 KB
    __shared__ u16 Bs[128][72];        // 18.4 KB
    __shared__ float STF[64][132];     // 33.8 KB fp32 epilogue staging
    const int tid = threadIdx.x;
    const int w = tid >> 6, l = tid & 63, q = l >> 4, r = l & 15;
    const int wm = w & 1, wn = w >> 1;
    const int m0 = blockIdx.x * 64;

    f32x4 acc[2][4] = {};

    #pragma unroll 1
    for (int k0 = 0; k0 < C2; k0 += 64) {
        __syncthreads();
        #pragma unroll
        for (int i = 0; i < 2; i++) {      // As: 64x64 u16 = 512 uint4
            int idx = tid + i * 256;
            int row = idx >> 3, g = (idx & 7) * 8;
            int gm = m0 + row;
            uint4 v = make_uint4(0u, 0u, 0u, 0u);
            if (gm < N) v = *(const uint4*)(A + (size_t)gm * C2 + k0 + g);
            *(uint4*)&As[row][g] = v;
        }
        #pragma unroll
        for (int i = 0; i < 4; i++) {      // Bs: 128x64 u16 = 1024 uint4
            int idx = tid + i * 256;
            int row = idx >> 3, g = (idx & 7) * 8;
            *(uint4*)&Bs[row][g] = *(const uint4*)(
                Bt + (size_t)row * C2 + k0 + g);   // Wmt is 128 x 256
        }
        __syncthreads();
        #pragma unroll
        for (int h = 0; h < 2; h++) {
            bf16x8 af[2], bfr[4];
            #pragma unroll
            for (int i = 0; i < 2; i++)
                af[i] = *(const bf16x8*)&As[wm * 32 + i * 16 + r][h * 32 + q * 8];
            #pragma unroll
            for (int j = 0; j < 4; j++)
                bfr[j] = *(const bf16x8*)&Bs[wn * 64 + j * 16 + r][h * 32 + q * 8];
            #pragma unroll
            for (int i = 0; i < 2; i++)
                #pragma unroll
                for (int j = 0; j < 4; j++)
                    acc[i][j] = __builtin_amdgcn_mfma_f32_16x16x32_bf16(
                        af[i], bfr[j], acc[i][j], 0, 0, 0);
        }
    }
    __syncthreads();

    // epilogue: stage fp32 tile in LDS, then full-line float4 flush (R9 lesson)
    #pragma unroll
    for (int j = 0; j < 4; j++) {
        const int ch = wn * 64 + j * 16 + r;
        const float bo = bias[ch];
        #pragma unroll
        for (int i = 0; i < 2; i++) {
            const int mb = wm * 32 + i * 16 + q * 4;
            #pragma unroll
            for (int p = 0; p < 4; p++)
                STF[mb + p][ch] = acc[i][j][p] + bo;
        }
    }
    __syncthreads();
    #pragma unroll
    for (int i = 0; i < 8; i++) {          // 64x128 fp32 = 2048 float4
        int idx = tid + i * 256;
        int row = idx >> 5, c4 = (idx & 31) * 4;
        if (m0 + row < N)
            *(float4*)(Cf + (size_t)(m0 + row) * C_OUT + c4) =
                *(const float4*)&STF[row][c4];
    }
}

// One wave per point: gather 16 packed rows, ONE dwordx4 per neighbor per lane
// (interleaved pairs -> e,x same lane). All 16 loads staged in registers
// (fully static indexing -> no scratch), then pool:
// feat[c] = (sum_k ey*x)/(sum_k ey).
__global__ __launch_bounds__(256)
void gather_k(const u16* __restrict__ packed, const int* __restrict__ nidx,
              u16* __restrict__ featb, int N)
{
    __shared__ int rows[4 * KNBR];
    const int tid = threadIdx.x;
    const int p0 = blockIdx.x * 4;

    if (tid < 4 * KNBR) {
        int n = p0 + (tid >> 4);
        rows[tid] = (n < N) ? nidx[n * KNBR + (tid & 15)] : 0;
    }
    __syncthreads();

    const int w = tid >> 6;       // wave id -> point p0+w
    const int l = tid & 63;       // channels 4l..4l+3 (pairs)
    const int p = p0 + w;
    if (p >= N) return;

    // issue all 16 row loads (16 B/lane, 1 KB/instruction, 16 KB in flight)
    u16x8 v[KNBR];
    #pragma unroll
    for (int k = 0; k < KNBR; k++)
        v[k] = *(const u16x8*)(packed + (size_t)rows[w * KNBR + k] * 512 + l * 8);

    float num[4] = {0.f, 0.f, 0.f, 0.f};
    float den[4] = {0.f, 0.f, 0.f, 0.f};
    #pragma unroll
    for (int k = 0; k < KNBR; k++) {
        #pragma unroll
        for (int c = 0; c < 4; c++) {
            float e = bf2f((u16)v[k][2 * c]);
            float x = bf2f((u16)v[k][2 * c + 1]);
            den[c] += e;
            num[c] = fmaf(e, x, num[c]);
        }
    }
    ushort4 o;
    o.x = f2bf(num[0] / den[0]); o.y = f2bf(num[1] / den[1]);
    o.z = f2bf(num[2] / den[2]); o.w = f2bf(num[3] / den[3]);
    *(ushort4*)(featb + (size_t)p * C2 + l * 4) = o;
}

extern "C" void kernel_launch(void* const* d_in, const int* in_sizes, int n_in,
                              void* d_out, int out_size, void* d_ws, size_t ws_size,
                              hipStream_t stream)
{
    const float* features = (const float*)d_in[0];
    const int*   nidx     = (const int*)d_in[1];
    const float* W1       = (const float*)d_in[2];
    const float* b1       = (const float*)d_in[3];
    const float* gamma    = (const float*)d_in[4];
    const float* beta     = (const float*)d_in[5];
    const float* mean     = (const float*)d_in[6];
    const float* var      = (const float*)d_in[7];
    const float* Ws       = (const float*)d_in[8];
    const float* Wm       = (const float*)d_in[9];
    const float* bm       = (const float*)d_in[10];
    float* out = (float*)d_out;

    const int N = in_sizes[0] / C_IN;   // 50000

    u16* packed = (u16*)d_ws;                      // N x 512 interleaved pairs
    u16* W1t    = packed + (size_t)N * 512;        // 256 x 128
    u16* Wst    = W1t + 256 * 128;                 // 256 x 256
    u16* Wmt    = Wst + 256 * 256;                 // 128 x 256
    // feat lives in d_out: bf16 N x 256 (512 B/row) == out fp32 N x 128
    // (512 B/row). out_gemm blocks read their own rows before writing.
    u16* featb = (u16*)d_out;

    prep_k<<<dim3(256, 3), 256, 0, stream>>>(W1, Ws, Wm, W1t, Wst, Wmt);

    const int MT = (N + 63) / 64;   // 782

    mlp_k<<<MT, 256, 0, stream>>>(features, W1t, Wst, b1, gamma, beta,
                                  mean, var, packed, N);
    gather_k<<<(N + 3) / 4, 256, 0, stream>>>(packed, nidx, featb, N);
    out_gemm<<<MT, 256, 0, stream>>>(featb, Wmt, bm, out, N);
}

// Round 2
// 254.962 us; speedup vs baseline: 1.0074x; 1.0074x over previous
//
#include <hip/hip_runtime.h>
#include <cstddef>

// Problem shape (fixed): N=50000, K=16, C_IN=128, C2=256, C_OUT=128.
#define C_IN  128
#define C2    256
#define C_OUT 128
#define KNBR  16
#define PTS   32     // points per gather_out block

typedef unsigned short u16;
typedef __attribute__((ext_vector_type(8))) short bf16x8;   // 8 bf16 (4 VGPRs)
typedef __attribute__((ext_vector_type(8))) unsigned short u16x8; // 16B payload
typedef __attribute__((ext_vector_type(4))) float f32x4;

__device__ __forceinline__ float bf2f(u16 h) {
    return __uint_as_float(((unsigned int)h) << 16);
}
__device__ __forceinline__ u16 f2bf(float x) {
    unsigned int u = __float_as_uint(x);
    return (u16)((u + 0x7fffu + ((u >> 16) & 1u)) >> 16);
}

// Transpose + convert weights to bf16, n-major [N][K].
__global__ void prep_k(const float* __restrict__ W1, const float* __restrict__ Ws,
                       const float* __restrict__ Wm, u16* __restrict__ W1t,
                       u16* __restrict__ Wst, u16* __restrict__ Wmt)
{
    const int n = blockIdx.x, t = threadIdx.x;
    if (blockIdx.y == 0) {
        if (t < 128) W1t[n * 128 + t] = f2bf(W1[t * 256 + n]);
    } else if (blockIdx.y == 1) {
        Wst[n * 256 + t] = f2bf(Ws[t * 256 + n]);
    } else {
        if (n < 128) Wmt[n * 256 + t] = f2bf(Wm[t * 128 + n]);
    }
}

// ---------------------------------------------------------------------------
// LESSONS ENCODED:
//  R7:  accumulator arrays indexed by non-unrolled loop vars spill to scratch.
//  R9:  scattered sub-dword global stores -> write-allocate RMW (16x bytes).
//  R10: 1-block/CU weight-stationary waves have zero latency hiding.
//  R11: packed row CHANNEL-INTERLEAVED [ey0,x0,ey1,x1,...]: one dwordx4/lane
//       per neighbor row; e,x same lane for the FMA.
//  R12 (this round): halving gather's VMEM instruction count changed NOTHING
//       (dur/FETCH identical) -> gather is pinned at ~3.4 TB/s on the L2-miss
//       path (random rows, no locality to recover, bf16 = precision floor).
//       So delete work instead: fuse gather+pool+output-GEMM. featb round-trip
//       (50 MB) and the out_gemm dispatch disappear; fp32 epilogue staging
//       aliases the feat LDS tile. 36.5 KB LDS -> 4 blocks/CU.
// packed row (512 u16): 256 pairs of (ey[c], x[c]), both bf16.
// ---------------------------------------------------------------------------

// Fused MLP, 64-row blocks (69.6 KB LDS -> 2 blocks/CU):
//   x  = BN(relu(F @ W1 + b1))  -> xs (LDS)
//   ey = exp(x @ Ws)            -> As reuse -> combined interleaved flush
__global__ __launch_bounds__(256)
void mlp_k(const float* __restrict__ F, const u16* __restrict__ W1t,
           const u16* __restrict__ Wst,
           const float* __restrict__ bias, const float* __restrict__ gamma,
           const float* __restrict__ beta, const float* __restrict__ mean,
           const float* __restrict__ var,
           u16* __restrict__ packed, int N)
{
    __shared__ u16 As[64][136];    // features tile (GEMM1); ey staging (epi 2)
    __shared__ u16 Bs[128][72];    // weight k-slice staging
    __shared__ u16 xs[64][264];    // x tile, full K=256

    const int tid = threadIdx.x;
    const int w = tid >> 6, l = tid & 63, q = l >> 4, r = l & 15;
    const int wm = w & 1, wn = w >> 1;
    const int m0 = blockIdx.x * 64;

    // stage As: 64 x 128 fp32 -> bf16 (2048 float4, 8/thread)
    #pragma unroll
    for (int i = 0; i < 8; i++) {
        int idx = tid + i * 256;
        int row = idx >> 5, c4 = (idx & 31) * 4;
        int gm = m0 + row;
        float4 v = make_float4(0.f, 0.f, 0.f, 0.f);
        if (gm < N) v = *(const float4*)(F + (size_t)gm * C_IN + c4);
        ushort4 h;
        h.x = f2bf(v.x); h.y = f2bf(v.y); h.z = f2bf(v.z); h.w = f2bf(v.w);
        *(ushort4*)&As[row][c4] = h;
    }

    // ---- GEMM1: x = F @ W1, two 128-col halves (nh fully unrolled) ----
    #pragma unroll
    for (int nh = 0; nh < 2; nh++) {
        f32x4 acc[2][4] = {};
        #pragma unroll 1
        for (int k0 = 0; k0 < C_IN; k0 += 64) {
            __syncthreads();   // prior Bs readers done (also covers As stage)
            #pragma unroll
            for (int i = 0; i < 4; i++) {
                int idx = tid + i * 256;
                int row = idx >> 3, g = (idx & 7) * 8;
                *(uint4*)&Bs[row][g] = *(const uint4*)(
                    W1t + (size_t)(nh * 128 + row) * C_IN + k0 + g);
            }
            __syncthreads();
            #pragma unroll
            for (int h = 0; h < 2; h++) {
                bf16x8 af[2], bfr[4];
                #pragma unroll
                for (int i = 0; i < 2; i++)
                    af[i] = *(const bf16x8*)&As[wm * 32 + i * 16 + r][k0 + h * 32 + q * 8];
                #pragma unroll
                for (int j = 0; j < 4; j++)
                    bfr[j] = *(const bf16x8*)&Bs[wn * 64 + j * 16 + r][h * 32 + q * 8];
                #pragma unroll
                for (int i = 0; i < 2; i++)
                    #pragma unroll
                    for (int j = 0; j < 4; j++)
                        acc[i][j] = __builtin_amdgcn_mfma_f32_16x16x32_bf16(
                            af[i], bfr[j], acc[i][j], 0, 0, 0);
            }
        }
        // epilogue 1: BN(relu(z+bias)) -> xs (LDS only)
        #pragma unroll
        for (int j = 0; j < 4; j++) {
            const int ch = nh * 128 + wn * 64 + j * 16 + r;
            const float bi = bias[ch], be = beta[ch], mu = mean[ch];
            const float iv = gamma[ch] * rsqrtf(var[ch] + 1e-5f);
            #pragma unroll
            for (int i = 0; i < 2; i++) {
                const int mb = wm * 32 + i * 16 + q * 4;
                #pragma unroll
                for (int p = 0; p < 4; p++) {
                    float x = fmaxf(acc[i][j][p] + bi, 0.f);
                    x = (x - mu) * iv + be;
                    xs[mb + p][ch] = f2bf(x);
                }
            }
        }
    }
    __syncthreads();   // xs complete (cross-wave) before GEMM2 reads it

    // ---- GEMM2: ey = exp(x @ Ws), A from xs (nh fully unrolled) ----
    #pragma unroll
    for (int nh = 0; nh < 2; nh++) {
        f32x4 acc[2][4] = {};
        #pragma unroll 1
        for (int k0 = 0; k0 < C2; k0 += 64) {
            __syncthreads();   // prior Bs readers / prior-half flush readers done
            #pragma unroll
            for (int i = 0; i < 4; i++) {
                int idx = tid + i * 256;
                int row = idx >> 3, g = (idx & 7) * 8;
                *(uint4*)&Bs[row][g] = *(const uint4*)(
                    Wst + (size_t)(nh * 128 + row) * C2 + k0 + g);
            }
            __syncthreads();
            #pragma unroll
            for (int h = 0; h < 2; h++) {
                bf16x8 af[2], bfr[4];
                #pragma unroll
                for (int i = 0; i < 2; i++)
                    af[i] = *(const bf16x8*)&xs[wm * 32 + i * 16 + r][k0 + h * 32 + q * 8];
                #pragma unroll
                for (int j = 0; j < 4; j++)
                    bfr[j] = *(const bf16x8*)&Bs[wn * 64 + j * 16 + r][h * 32 + q * 8];
                #pragma unroll
                for (int i = 0; i < 2; i++)
                    #pragma unroll
                    for (int j = 0; j < 4; j++)
                        acc[i][j] = __builtin_amdgcn_mfma_f32_16x16x32_bf16(
                            af[i], bfr[j], acc[i][j], 0, 0, 0);
            }
        }
        // epilogue 2: ey -> As reuse (cols local to this nh-half)
        __syncthreads();       // prior As readers (GEMM1 / prev flush) done
        #pragma unroll
        for (int j = 0; j < 4; j++) {
            const int chl = wn * 64 + j * 16 + r;   // 0..127 within half
            #pragma unroll
            for (int i = 0; i < 2; i++) {
                const int mb = wm * 32 + i * 16 + q * 4;
                #pragma unroll
                for (int p = 0; p < 4; p++)
                    As[mb + p][chl] = f2bf(__expf(acc[i][j][p]));
            }
        }
        __syncthreads();       // As (ey half) complete
        // combined interleaved flush for this half:
        // 64 rows x 128 pairs -> 64 x 512 B (2048 uint4, 8/thread).
        #pragma unroll
        for (int i = 0; i < 8; i++) {
            int idx = tid + i * 256;
            int row = idx >> 5, slot = idx & 31;   // slot: uint4 within row-half
            int c0 = slot * 4;                     // first local channel of 4
            if (m0 + row < N) {
                ushort4 e  = *(const ushort4*)&As[row][c0];
                ushort4 xv = *(const ushort4*)&xs[row][nh * 128 + c0];
                uint4 qv;
                qv.x = (unsigned)e.x | ((unsigned)xv.x << 16);
                qv.y = (unsigned)e.y | ((unsigned)xv.y << 16);
                qv.z = (unsigned)e.z | ((unsigned)xv.z << 16);
                qv.w = (unsigned)e.w | ((unsigned)xv.w << 16);
                *(uint4*)(packed + (size_t)(m0 + row) * 512 + nh * 256 + slot * 8) = qv;
            }
        }
    }
}

// Fused gather + attentive pool + output GEMM. 32 points/block, 4 waves.
// Phase 1: each wave pools 8 points (16 x 1KB random rows each) -> feat LDS
//          tile [32][264] bf16 (lane l owns channels 4l..4l+3).
// Phase 2: out[32 x 128] = feat @ Wmt + bm via MFMA, K=256 in 4 k-steps;
//          fp32 epilogue staging ALIASES the feat buffer (feat fully consumed).
// LDS: 2KB rows + 18.4KB Bs + 16.9KB feat/STF = 37.4KB -> 4 blocks/CU.
__global__ __launch_bounds__(256)
void gather_out_k(const u16* __restrict__ packed, const int* __restrict__ nidx,
                  const u16* __restrict__ Bt, const float* __restrict__ bias,
                  float* __restrict__ Cf, int N)
{
    __shared__ int rows[PTS * KNBR];                 // 2 KB
    __shared__ u16 Bs[128][72];                      // 18.4 KB
    __shared__ __align__(16) u16 fsm[PTS * 264];     // feat bf16 / STF fp32 alias

    const int tid = threadIdx.x;
    const int w = tid >> 6, l = tid & 63, q = l >> 4, r = l & 15;
    const int m0 = blockIdx.x * PTS;

    // stage neighbor indices: PTS*16 = 512 ints, 2/thread
    #pragma unroll
    for (int i = 0; i < 2; i++) {
        int idx = tid + i * 256;
        int n = m0 + (idx >> 4);
        rows[idx] = (n < N) ? nidx[n * KNBR + (idx & 15)] : 0;
    }
    __syncthreads();

    // ---- phase 1: gather + pool, wave w -> points w*8 .. w*8+7 ----
    #pragma unroll 1
    for (int ip = 0; ip < 8; ip++) {
        const int pl = w * 8 + ip;
        u16x8 v[KNBR];
        #pragma unroll
        for (int k = 0; k < KNBR; k++)
            v[k] = *(const u16x8*)(packed + (size_t)rows[pl * KNBR + k] * 512 + l * 8);
        float num[4] = {0.f, 0.f, 0.f, 0.f};
        float den[4] = {0.f, 0.f, 0.f, 0.f};
        #pragma unroll
        for (int k = 0; k < KNBR; k++) {
            #pragma unroll
            for (int c = 0; c < 4; c++) {
                float e = bf2f((u16)v[k][2 * c]);
                float x = bf2f((u16)v[k][2 * c + 1]);
                den[c] += e;
                num[c] = fmaf(e, x, num[c]);
            }
        }
        ushort4 o;
        o.x = f2bf(num[0] / den[0]); o.y = f2bf(num[1] / den[1]);
        o.z = f2bf(num[2] / den[2]); o.w = f2bf(num[3] / den[3]);
        *(ushort4*)&fsm[pl * 264 + l * 4] = o;   // rows >= N: garbage, never stored
    }
    __syncthreads();   // feat tile complete

    // ---- phase 2: out GEMM, wave grid 2M x 2N (16 rows x 64 cols per wave) ----
    const int wm = w & 1, wn = w >> 1;
    f32x4 acc[4] = {};

    #pragma unroll 1
    for (int k0 = 0; k0 < C2; k0 += 64) {
        __syncthreads();
        #pragma unroll
        for (int i = 0; i < 4; i++) {      // Bs: 128x64 u16 = 1024 uint4
            int idx = tid + i * 256;
            int row = idx >> 3, g = (idx & 7) * 8;
            *(uint4*)&Bs[row][g] = *(const uint4*)(
                Bt + (size_t)row * C2 + k0 + g);   // Wmt is 128 x 256
        }
        __syncthreads();
        #pragma unroll
        for (int h = 0; h < 2; h++) {
            bf16x8 af, bfr[4];
            af = *(const bf16x8*)&fsm[(wm * 16 + r) * 264 + k0 + h * 32 + q * 8];
            #pragma unroll
            for (int j = 0; j < 4; j++)
                bfr[j] = *(const bf16x8*)&Bs[wn * 64 + j * 16 + r][h * 32 + q * 8];
            #pragma unroll
            for (int j = 0; j < 4; j++)
                acc[j] = __builtin_amdgcn_mfma_f32_16x16x32_bf16(
                    af, bfr[j], acc[j], 0, 0, 0);
        }
    }
    __syncthreads();   // all feat reads done -> safe to alias STF onto fsm

    // epilogue: stage fp32 tile in aliased LDS, then full-line float4 flush
    float* STF = (float*)fsm;              // [32][132]
    #pragma unroll
    for (int j = 0; j < 4; j++) {
        const int ch = wn * 64 + j * 16 + r;
        const float bo = bias[ch];
        const int mb = wm * 16 + q * 4;
        #pragma unroll
        for (int p = 0; p < 4; p++)
            STF[(mb + p) * 132 + ch] = acc[j][p] + bo;
    }
    __syncthreads();
    #pragma unroll
    for (int i = 0; i < 4; i++) {          // 32x128 fp32 = 1024 float4
        int idx = tid + i * 256;
        int row = idx >> 5, c4 = (idx & 31) * 4;
        if (m0 + row < N)
            *(float4*)(Cf + (size_t)(m0 + row) * C_OUT + c4) =
                *(const float4*)&STF[row * 132 + c4];
    }
}

extern "C" void kernel_launch(void* const* d_in, const int* in_sizes, int n_in,
                              void* d_out, int out_size, void* d_ws, size_t ws_size,
                              hipStream_t stream)
{
    const float* features = (const float*)d_in[0];
    const int*   nidx     = (const int*)d_in[1];
    const float* W1       = (const float*)d_in[2];
    const float* b1       = (const float*)d_in[3];
    const float* gamma    = (const float*)d_in[4];
    const float* beta     = (const float*)d_in[5];
    const float* mean     = (const float*)d_in[6];
    const float* var      = (const float*)d_in[7];
    const float* Ws       = (const float*)d_in[8];
    const float* Wm       = (const float*)d_in[9];
    const float* bm       = (const float*)d_in[10];
    float* out = (float*)d_out;

    const int N = in_sizes[0] / C_IN;   // 50000

    u16* packed = (u16*)d_ws;                      // N x 512 interleaved pairs
    u16* W1t    = packed + (size_t)N * 512;        // 256 x 128
    u16* Wst    = W1t + 256 * 128;                 // 256 x 256
    u16* Wmt    = Wst + 256 * 256;                 // 128 x 256

    prep_k<<<dim3(256, 3), 256, 0, stream>>>(W1, Ws, Wm, W1t, Wst, Wmt);

    const int MT = (N + 63) / 64;    // 782
    const int GT = (N + PTS - 1) / PTS;  // 1563

    mlp_k<<<MT, 256, 0, stream>>>(features, W1t, Wst, b1, gamma, beta,
                                  mean, var, packed, N);
    gather_out_k<<<GT, 256, 0, stream>>>(packed, nidx, Wmt, bm, out, N);
}